// Round 7
// baseline (493.848 us; speedup 1.0000x reference)
//
#include <hip/hip_runtime.h>
#include <math.h>

typedef __bf16 bf16_t;
typedef __bf16 bf16x4 __attribute__((ext_vector_type(4)));
typedef __bf16 bf16x8 __attribute__((ext_vector_type(8)));
typedef float  f32x4  __attribute__((ext_vector_type(4)));

#define FNUM 256
#define KPAD 608          // 600 padded to 608 (19 K-steps of 32)
#define NKS  19
#define BUFE (65*300)     // 19500 bf16 elements per X buffer (65 rows)
#define BUFG (BUFE + 8)   // + guard for k=600..607 overrun of last row

// ---------------- W prep: f32 [256][600] -> swizzled bf16 MFMA-fragment tiles ----------------
// Tile (ks, ft): 64 lanes x 8 bf16 contiguous. lane l -> f = ft*16+(l&15), k = ks*32+(l>>4)*8+e.
__global__ __launch_bounds__(256)
void prep_w_swz(const float* __restrict__ w0, const float* __restrict__ w1,
                const float* __restrict__ w2, const float* __restrict__ w3,
                const float* __restrict__ w4, bf16_t* __restrict__ wp) {
    int tg = blockIdx.x * 4 + (threadIdx.x >> 6);    // 5*19*16 = 1520 tiles
    if (tg >= 1520) return;
    int l  = threadIdx.x & 63;
    int br = tg / 304;
    int rem = tg % 304;
    int ks = rem / 16, ft = rem % 16;
    const float* src;
    switch (br) {
        case 0: src = w0; break;
        case 1: src = w1; break;
        case 2: src = w2; break;
        case 3: src = w3; break;
        default: src = w4; break;
    }
    int f = ft * 16 + (l & 15);
    int k0 = ks * 32 + (l >> 4) * 8;
    bf16x8 v;
#pragma unroll
    for (int e = 0; e < 8; e++) {
        int k = k0 + e;
        v[e] = (k < 600) ? (bf16_t)src[(size_t)f * 600 + k] : (bf16_t)0.f;
    }
    *(bf16x8*)(wp + (size_t)br * FNUM * KPAD + ((size_t)(ks * 16 + ft) * 512 + (size_t)l * 8)) = v;
}

// ---------------- pipelined K-loop: 8 waves, wave w owns f [32w,32w+32), full 64-t tile ----------------
// W streamed per step (no reg prefetch; unroll lets compiler hoist). Staging of the NEXT
// chunk is quartered: <=3 float4 live at once. Caller barriers once per chunk.
__device__ __forceinline__ void kloop(const bf16_t* __restrict__ wa,
    const bf16_t* __restrict__ bufR, bf16_t* __restrict__ bufW,
    f32x4 (&acc)[2][4], const int nf, const bool doStage,
    const float* __restrict__ srcN, const int nvalidN, const int nfullN,
    const int tid, const int l15, const int g) {
    float4 st[3];
    const int bo0 = l15 * 300 + g * 8;
#pragma unroll
    for (int ks = 0; ks < NKS; ++ks) {
        if (doStage) {
            // quarters: slots {0,1,2} {3,4,5} {6,7} {8,9}; load at 1/5/9/13, write at 4/8/12/16
            if (ks == 1) {
#pragma unroll
                for (int q = 0; q < 3; q++) {
                    int v = tid + q * 512;
                    float4 z = {0.f, 0.f, 0.f, 0.f};
                    st[q] = (v < nvalidN) ? *(const float4*)(srcN + (size_t)v * 4) : z;
                }
            }
            if (ks == 4) {
#pragma unroll
                for (int q = 0; q < 3; q++) {
                    int v = tid + q * 512;
                    if (v < nfullN) {
                        bf16x4 hv = { (bf16_t)st[q].x, (bf16_t)st[q].y,
                                      (bf16_t)st[q].z, (bf16_t)st[q].w };
                        *(bf16x4*)(bufW + v * 4) = hv;
                    }
                }
            }
            if (ks == 5) {
#pragma unroll
                for (int q = 0; q < 3; q++) {
                    int v = tid + (q + 3) * 512;
                    float4 z = {0.f, 0.f, 0.f, 0.f};
                    st[q] = (v < nvalidN) ? *(const float4*)(srcN + (size_t)v * 4) : z;
                }
            }
            if (ks == 8) {
#pragma unroll
                for (int q = 0; q < 3; q++) {
                    int v = tid + (q + 3) * 512;
                    if (v < nfullN) {
                        bf16x4 hv = { (bf16_t)st[q].x, (bf16_t)st[q].y,
                                      (bf16_t)st[q].z, (bf16_t)st[q].w };
                        *(bf16x4*)(bufW + v * 4) = hv;
                    }
                }
            }
            if (ks == 9) {
#pragma unroll
                for (int q = 0; q < 2; q++) {
                    int v = tid + (q + 6) * 512;
                    float4 z = {0.f, 0.f, 0.f, 0.f};
                    st[q] = (v < nvalidN) ? *(const float4*)(srcN + (size_t)v * 4) : z;
                }
            }
            if (ks == 12) {
#pragma unroll
                for (int q = 0; q < 2; q++) {
                    int v = tid + (q + 6) * 512;
                    if (v < nfullN) {
                        bf16x4 hv = { (bf16_t)st[q].x, (bf16_t)st[q].y,
                                      (bf16_t)st[q].z, (bf16_t)st[q].w };
                        *(bf16x4*)(bufW + v * 4) = hv;
                    }
                }
            }
            if (ks == 13) {
#pragma unroll
                for (int q = 0; q < 2; q++) {
                    int v = tid + (q + 8) * 512;
                    float4 z = {0.f, 0.f, 0.f, 0.f};
                    st[q] = (v < nvalidN) ? *(const float4*)(srcN + (size_t)v * 4) : z;
                }
            }
            if (ks == 16) {
#pragma unroll
                for (int q = 0; q < 2; q++) {
                    int v = tid + (q + 8) * 512;
                    if (v < nfullN) {
                        bf16x4 hv = { (bf16_t)st[q].x, (bf16_t)st[q].y,
                                      (bf16_t)st[q].z, (bf16_t)st[q].w };
                        *(bf16x4*)(bufW + v * 4) = hv;
                    }
                }
            }
        }
        const int k0 = ks * 32;
        const bf16_t* wk = wa + (size_t)ks * (16 * 512);
        bf16x8 a0 = *(const bf16x8*)(wk);
        bf16x8 a1 = *(const bf16x8*)(wk + 512);
#pragma unroll
        for (int j = 0; j < 4; j++) {
            if (j < nf) {
                const bf16_t* p = bufR + bo0 + j * (16 * 300) + k0;
                bf16x4 lo = *(const bf16x4*)(p);
                bf16x4 hi = *(const bf16x4*)(p + 4);
                bf16x8 bb = __builtin_shufflevector(lo, hi, 0, 1, 2, 3, 4, 5, 6, 7);
                acc[0][j] = __builtin_amdgcn_mfma_f32_16x16x32_bf16(a0, bb, acc[0][j], 0, 0, 0);
                acc[1][j] = __builtin_amdgcn_mfma_f32_16x16x32_bf16(a1, bb, acc[1][j], 0, 0, 0);
            }
        }
    }
}

// ---------------- body conv: grid 1028; bid<1024 = batch (4 chunks pipelined, normalize -> nebT col);
// bid>=1024 = doc chunk (bid-1024), partial sums -> mdp ----------------
__global__ __launch_bounds__(512, 4)
void conv_body(const float* __restrict__ X, const bf16_t* __restrict__ Wsw,
               const float* __restrict__ bias, float* __restrict__ nebT,
               const float* __restrict__ Xdoc, const bf16_t* __restrict__ Wdoc,
               const float* __restrict__ bdoc, float* __restrict__ mdp) {
    __shared__ bf16_t Xl[2][BUFG];
    __shared__ float feat[256];
    __shared__ float red[8];
    const int tid = threadIdx.x, l = tid & 63, w = tid >> 6, g = l >> 4, l15 = l & 15;
    const bool rider = ((int)blockIdx.x >= 1024);

    const float*  Xb = rider ? Xdoc : X + (size_t)blockIdx.x * 60000;
    const bf16_t* Wb = rider ? Wdoc : Wsw;
    const float*  bp = rider ? bdoc : bias;
    const bf16_t* wa = Wb + (size_t)(2 * w) * 512 + (size_t)l * 8;

    // zero the fixed k-overrun guards of both buffers
    if (tid < 8) { Xl[0][BUFE + tid] = (bf16_t)0.f; Xl[1][BUFE + tid] = (bf16_t)0.f; }

    const int cFirst = rider ? ((int)blockIdx.x - 1024) : 0;
    const int cCount = rider ? 1 : 4;

    // prologue: stage chunk cFirst into buf0
    {
        int nf0 = (cFirst < 3) ? 4 : 1;
        int rows = nf0 * 16 + 1;
        int vr = 200 - 64 * cFirst; if (vr > rows) vr = rows;
        const float* src = Xb + (size_t)(64 * cFirst) * 300;
        int nvalid = vr * 75, nfull = rows * 75;
        for (int v = tid; v < nfull; v += 512) {
            float4 fv = {0.f, 0.f, 0.f, 0.f};
            if (v < nvalid) fv = *(const float4*)(src + (size_t)v * 4);
            bf16x4 hv = { (bf16_t)fv.x, (bf16_t)fv.y, (bf16_t)fv.z, (bf16_t)fv.w };
            *(bf16x4*)(&Xl[0][0] + v * 4) = hv;
        }
    }
    __syncthreads();

    float run[2][4] = {{0.f,0.f,0.f,0.f},{0.f,0.f,0.f,0.f}};
    int pp = 0;
    for (int cc = 0; cc < cCount; ++cc) {
        const int c  = cFirst + cc;
        const int nf = (c < 3) ? 4 : 1;
        f32x4 acc[2][4];
#pragma unroll
        for (int i = 0; i < 2; i++)
#pragma unroll
            for (int j = 0; j < 4; j++) acc[i][j] = (f32x4){0.f, 0.f, 0.f, 0.f};

        const bool doStage = (cc + 1 < cCount);
        int nvalidN = 0, nfullN = 0;
        const float* srcN = nullptr;
        if (doStage) {
            int c1 = c + 1;
            int nf1 = (c1 < 3) ? 4 : 1;
            int rows1 = nf1 * 16 + 1;
            int vr1 = 200 - 64 * c1; if (vr1 > rows1) vr1 = rows1;
            srcN = Xb + (size_t)(64 * c1) * 300;
            nvalidN = vr1 * 75; nfullN = rows1 * 75;
        }

        kloop(wa, &Xl[pp][0], &Xl[pp ^ 1][0], acc, nf, doStage, srcN, nvalidN, nfullN, tid, l15, g);

        // epilogue: relu(acc+bias), t-mask, accumulate (bias loaded here, not held in kloop)
#pragma unroll
        for (int i = 0; i < 2; i++)
#pragma unroll
            for (int r = 0; r < 4; r++) {
                const float bi = bp[32 * w + i * 16 + g * 4 + r];
                float s = run[i][r];
#pragma unroll
                for (int j = 0; j < 4; j++) {
                    if (j < nf) {
                        int t = 64 * c + j * 16 + l15;
                        float v = acc[i][j][r] + bi;
                        v = fmaxf(v, 0.f);
                        s += (t < 199) ? v : 0.f;
                    }
                }
                run[i][r] = s;
            }
        __syncthreads();
        pp ^= 1;
    }

    // cross-lane t-reduce -> feat
#pragma unroll
    for (int i = 0; i < 2; i++)
#pragma unroll
        for (int r = 0; r < 4; r++) {
            float s = run[i][r];
            s += __shfl_xor(s, 1);
            s += __shfl_xor(s, 2);
            s += __shfl_xor(s, 4);
            s += __shfl_xor(s, 8);
            if (l15 == 0) feat[32 * w + i * 16 + g * 4 + r] = s;
        }
    __syncthreads();

    if (rider) {
        if (tid < 256) mdp[(size_t)(blockIdx.x - 1024) * 256 + tid] = feat[tid];
        return;
    }
    float v = 0.f, sq = 0.f;
    if (tid < 256) { v = feat[tid]; sq = v * v; }
    sq += __shfl_xor(sq, 1);
    sq += __shfl_xor(sq, 2);
    sq += __shfl_xor(sq, 4);
    sq += __shfl_xor(sq, 8);
    sq += __shfl_xor(sq, 16);
    sq += __shfl_xor(sq, 32);
    if (l == 0) red[w] = sq;
    __syncthreads();
    float tot = red[0] + red[1] + red[2] + red[3];
    if (tid < 256) nebT[(size_t)tid * 1024 + blockIdx.x] = v / sqrtf(tot);
}

// ---------------- small branches (title/context/mention), one kernel, grid 1536 ----------------
__global__ __launch_bounds__(512, 4)
void conv_small(const float* __restrict__ title, const bf16_t* __restrict__ Wet,
                const float* __restrict__ bet, float* __restrict__ netT,
                const float* __restrict__ ctx, const bf16_t* __restrict__ Wmc,
                const float* __restrict__ bmc, float* __restrict__ nmc,
                const float* __restrict__ men, const bf16_t* __restrict__ Wms,
                const float* __restrict__ bms, float* __restrict__ nms) {
    __shared__ bf16_t Xs[33 * 300 + 8];
    __shared__ float feat[256];
    __shared__ float red[8];
    const int tid = threadIdx.x, l = tid & 63, w = tid >> 6, g = l >> 4, l15 = l & 15;
    const int bid = blockIdx.x;

    const float* Xb; const bf16_t* Wb; const float* bp;
    int L, T, nf, batch, mode;
    if (bid < 1024)      { mode = 0; batch = bid;        Xb = title + (size_t)batch * 6000; Wb = Wet; bp = bet; L = 20; T = 19; nf = 2; }
    else if (bid < 1280) { mode = 1; batch = bid - 1024; Xb = ctx   + (size_t)batch * 6000; Wb = Wmc; bp = bmc; L = 20; T = 19; nf = 2; }
    else                 { mode = 2; batch = bid - 1280; Xb = men   + (size_t)batch * 3000; Wb = Wms; bp = bms; L = 10; T = 9;  nf = 1; }

    const bf16_t* wa = Wb + (size_t)(2 * w) * 512 + (size_t)l * 8;

    // stage single chunk
    {
        int rows = nf * 16 + 1;
        int vr = (L < rows) ? L : rows;
        int nvalid = vr * 75, nfull = rows * 75;
        for (int v = tid; v < nfull; v += 512) {
            float4 fv = {0.f, 0.f, 0.f, 0.f};
            if (v < nvalid) fv = *(const float4*)(Xb + (size_t)v * 4);
            bf16x4 hv = { (bf16_t)fv.x, (bf16_t)fv.y, (bf16_t)fv.z, (bf16_t)fv.w };
            *(bf16x4*)(Xs + v * 4) = hv;
        }
        if (tid < 8) Xs[nfull * 4 + tid] = (bf16_t)0.f;
    }
    __syncthreads();

    f32x4 acc[2][4];
#pragma unroll
    for (int i = 0; i < 2; i++)
#pragma unroll
        for (int j = 0; j < 4; j++) acc[i][j] = (f32x4){0.f, 0.f, 0.f, 0.f};

    kloop(wa, Xs, Xs, acc, nf, false, nullptr, 0, 0, tid, l15, g);

#pragma unroll
    for (int i = 0; i < 2; i++)
#pragma unroll
        for (int r = 0; r < 4; r++) {
            const float bi = bp[32 * w + i * 16 + g * 4 + r];
            float s = 0.f;
#pragma unroll
            for (int j = 0; j < 4; j++) {
                if (j < nf) {
                    int t = j * 16 + l15;
                    float v = acc[i][j][r] + bi;
                    v = fmaxf(v, 0.f);
                    s += (t < T) ? v : 0.f;
                }
            }
            s += __shfl_xor(s, 1);
            s += __shfl_xor(s, 2);
            s += __shfl_xor(s, 4);
            s += __shfl_xor(s, 8);
            if (l15 == 0) feat[32 * w + i * 16 + g * 4 + r] = s;
        }
    __syncthreads();

    float v = 0.f, sq = 0.f;
    if (tid < 256) { v = feat[tid]; sq = v * v; }
    sq += __shfl_xor(sq, 1);
    sq += __shfl_xor(sq, 2);
    sq += __shfl_xor(sq, 4);
    sq += __shfl_xor(sq, 8);
    sq += __shfl_xor(sq, 16);
    sq += __shfl_xor(sq, 32);
    if (l == 0) red[w] = sq;
    __syncthreads();
    float tot = red[0] + red[1] + red[2] + red[3];
    if (tid < 256) {
        float o = v / sqrtf(tot);
        if (mode == 0)      netT[(size_t)tid * 1024 + batch] = o;
        else if (mode == 1) nmc[(size_t)batch * 256 + tid] = o;
        else                nms[(size_t)batch * 256 + tid] = o;
    }
}

// ---------------- dt/db: combine doc partials, normalize, dot with netT/nebT columns ----------------
__global__ __launch_bounds__(256)
void dt_db_kernel(const float* __restrict__ mdp, const float* __restrict__ netT,
                  const float* __restrict__ nebT, float* __restrict__ dt,
                  float* __restrict__ db) {
    __shared__ float md[256];
    __shared__ float red[4];
    int tid = threadIdx.x;
    float m = mdp[tid] + mdp[256 + tid] + mdp[512 + tid] + mdp[768 + tid];
    float sq = m * m;
    sq += __shfl_xor(sq, 1);
    sq += __shfl_xor(sq, 2);
    sq += __shfl_xor(sq, 4);
    sq += __shfl_xor(sq, 8);
    sq += __shfl_xor(sq, 16);
    sq += __shfl_xor(sq, 32);
    if ((tid & 63) == 0) red[tid >> 6] = sq;
    __syncthreads();
    float rn = 1.f / sqrtf(red[0] + red[1] + red[2] + red[3]);
    md[tid] = m * rn;
    __syncthreads();
    int n = blockIdx.x * 256 + tid;
    float dT = 0.f, dB = 0.f;
    for (int k = 0; k < 256; ++k) {
        float mk = md[k];
        dT += mk * netT[(size_t)k * 1024 + n];
        dB += mk * nebT[(size_t)k * 1024 + n];
    }
    dt[n] = dT;
    db[n] = dB;
}

// ---------------- pair pass 1: tile 4m x 256n per block (grid 256), scores + raw e + partial sums ----------------
__global__ __launch_bounds__(256)
void pair1(const float* __restrict__ nms, const float* __restrict__ nmc,
           const float* __restrict__ netT, const float* __restrict__ nebT,
           const float* __restrict__ dt, const float* __restrict__ db,
           const float* __restrict__ wl, const float* __restrict__ bl,
           const int* __restrict__ me, float* __restrict__ out,
           float* __restrict__ epart) {
    __shared__ float sA[4 * 256], sB[4 * 256];
    const int tid = threadIdx.x;
    const int mt = blockIdx.x >> 2;
    const int nt = blockIdx.x & 3;
    const int m0 = mt * 4, n0 = nt * 256;
    for (int v = tid; v < 1024; v += 256) {
        sA[v] = nms[(size_t)m0 * 256 + v];
        sB[v] = nmc[(size_t)m0 * 256 + v];
    }
    __syncthreads();
    const int ws = tid >> 6;
    const int nl = tid & 63;
    const int n  = n0 + nl * 4;
    const int m  = m0 + ws;

    float dst[4] = {0,0,0,0}, dct[4] = {0,0,0,0}, dsb[4] = {0,0,0,0}, dcb[4] = {0,0,0,0};
    for (int k = 0; k < 256; ++k) {
        float4 tv = *(const float4*)(netT + (size_t)k * 1024 + n);
        float4 bv = *(const float4*)(nebT + (size_t)k * 1024 + n);
        float a = sA[ws * 256 + k];
        float c = sB[ws * 256 + k];
        dst[0] += a * tv.x; dst[1] += a * tv.y; dst[2] += a * tv.z; dst[3] += a * tv.w;
        dct[0] += c * tv.x; dct[1] += c * tv.y; dct[2] += c * tv.z; dct[3] += c * tv.w;
        dsb[0] += a * bv.x; dsb[1] += a * bv.y; dsb[2] += a * bv.z; dsb[3] += a * bv.w;
        dcb[0] += c * bv.x; dcb[1] += c * bv.y; dcb[2] += c * bv.z; dcb[3] += c * bv.w;
    }

    float w0 = wl[0], w1 = wl[1], w2 = wl[2], w3 = wl[3], w4 = wl[4], w5 = wl[5], b = bl[0];
    float dtq[4], dbq[4];
    *(float4*)dtq = *(const float4*)(dt + n);
    *(float4*)dbq = *(const float4*)(db + n);
    const int* mp = me + (size_t)m * 1024 + n;
    float scv[4], evv[4];
    float esum = 0.f;
#pragma unroll
    for (int q = 0; q < 4; q++) {
        float msk = (float)mp[q];
        float f_st = dst[q] * 0.5f + 0.5f;
        float f_dt = dtq[q] * 0.5f + 0.5f;
        float f_ct = dct[q] * 0.5f + 0.5f;
        float f_sb = dsb[q] * 0.5f + 0.5f;
        float f_db = dbq[q] * 0.5f + 0.5f;
        float f_cb = dcb[q] * 0.5f + 0.5f;
        float s = f_st * w0 + f_dt * w1 + f_ct * w2 + f_sb * w3 + f_db * w4 + f_cb * w5 + b;
        s = (msk != 0.f) ? s : 0.f;
        scv[q] = s;
        evv[q] = (msk != 0.f) ? expf(s / 0.1f) : 0.f;
        esum += evv[q];
    }
    esum += __shfl_xor(esum, 1);
    esum += __shfl_xor(esum, 2);
    esum += __shfl_xor(esum, 4);
    esum += __shfl_xor(esum, 8);
    esum += __shfl_xor(esum, 16);
    esum += __shfl_xor(esum, 32);
    if (nl == 0) epart[(size_t)m * 4 + nt] = esum;

    *(float4*)(out + (size_t)m * 1024 + n) = *(float4*)scv;
    *(float4*)(out + 262144 + (size_t)m * 1024 + n) = *(float4*)evv;
}

// ---------------- pair pass 2: row-normalize e in place ----------------
__global__ __launch_bounds__(256)
void pair2(const float* __restrict__ epart, float* __restrict__ out2) {
    int m = blockIdx.x, tid = threadIdx.x;
    float tot = epart[(size_t)m * 4 + 0] + epart[(size_t)m * 4 + 1]
              + epart[(size_t)m * 4 + 2] + epart[(size_t)m * 4 + 3];
    float inv = 1.f / tot;
#pragma unroll
    for (int q = 0; q < 4; q++)
        out2[(size_t)m * 1024 + q * 256 + tid] *= inv;
}

extern "C" void kernel_launch(void* const* d_in, const int* in_sizes, int n_in,
                              void* d_out, int out_size, void* d_ws, size_t ws_size,
                              hipStream_t stream) {
    const float* mention = (const float*)d_in[0];
    const float* context = (const float*)d_in[1];
    const float* doc     = (const float*)d_in[2];
    const float* title   = (const float*)d_in[3];
    const float* body    = (const float*)d_in[4];
    const float* W_ms = (const float*)d_in[5];  const float* b_ms = (const float*)d_in[6];
    const float* W_mc = (const float*)d_in[7];  const float* b_mc = (const float*)d_in[8];
    const float* W_md = (const float*)d_in[9];  const float* b_md = (const float*)d_in[10];
    const float* W_et = (const float*)d_in[11]; const float* b_et = (const float*)d_in[12];
    const float* W_eb = (const float*)d_in[13]; const float* b_eb = (const float*)d_in[14];
    const float* w_local = (const float*)d_in[15];
    const float* b_local = (const float*)d_in[16];
    const int*   me      = (const int*)d_in[17];
    float* out = (float*)d_out;

    char* ws = (char*)d_ws;
    bf16_t* Wp = (bf16_t*)ws;
    size_t off = (size_t)5 * FNUM * KPAD * 2;             // swizzled W: 1,556,480 B
    float* nms  = (float*)(ws + off); off += 256 * 256 * 4;
    float* nmc  = (float*)(ws + off); off += 256 * 256 * 4;
    float* netT = (float*)(ws + off); off += 256 * 1024 * 4;
    float* nebT = (float*)(ws + off); off += 256 * 1024 * 4;
    float* mdp  = (float*)(ws + off); off += 4 * 256 * 4;
    float* dt   = (float*)(ws + off); off += 1024 * 4;
    float* db   = (float*)(ws + off); off += 1024 * 4;
    float* epart= (float*)(ws + off); off += 256 * 4 * 4;

    const bf16_t* Wms = Wp + (size_t)0 * FNUM * KPAD;
    const bf16_t* Wmc = Wp + (size_t)1 * FNUM * KPAD;
    const bf16_t* Wmd = Wp + (size_t)2 * FNUM * KPAD;
    const bf16_t* Wet = Wp + (size_t)3 * FNUM * KPAD;
    const bf16_t* Web = Wp + (size_t)4 * FNUM * KPAD;

    prep_w_swz<<<380, 256, 0, stream>>>(W_ms, W_mc, W_md, W_et, W_eb, Wp);

    conv_body<<<1028, 512, 0, stream>>>(body, Web, b_eb, nebT, doc, Wmd, b_md, mdp);
    conv_small<<<1536, 512, 0, stream>>>(title, Wet, b_et, netT,
                                         context, Wmc, b_mc, nmc,
                                         mention, Wms, b_ms, nms);

    dt_db_kernel<<<4, 256, 0, stream>>>(mdp, netT, nebT, dt, db);
    pair1<<<256, 256, 0, stream>>>(nms, nmc, netT, nebT, dt, db, w_local, b_local, me, out, epart);
    pair2<<<256, 256, 0, stream>>>(epart, out + 262144);
}

// Round 8
// 444.095 us; speedup vs baseline: 1.1120x; 1.1120x over previous
//
#include <hip/hip_runtime.h>
#include <math.h>

typedef __bf16 bf16_t;
typedef __bf16 bf16x4 __attribute__((ext_vector_type(4)));
typedef __bf16 bf16x8 __attribute__((ext_vector_type(8)));
typedef float  f32x4  __attribute__((ext_vector_type(4)));

#define FNUM 256
#define KPAD 608            // 600 padded to 608 (19 K-steps of 32)
#define NKS  19
#define BUFF 9908           // f32 elems per X buffer: 33 rows * 300 + 8 guard

// ---------------- W prep: f32 [256][600] -> swizzled bf16 MFMA-fragment tiles ----------------
// Tile (ks, ft): 64 lanes x 8 bf16 contiguous. lane l -> f = ft*16+(l&15), k = ks*32+(l>>4)*8+e.
__global__ __launch_bounds__(256)
void prep_w_swz(const float* __restrict__ w0, const float* __restrict__ w1,
                const float* __restrict__ w2, const float* __restrict__ w3,
                const float* __restrict__ w4, bf16_t* __restrict__ wp) {
    int tg = blockIdx.x * 4 + (threadIdx.x >> 6);    // 5*19*16 = 1520 tiles
    if (tg >= 1520) return;
    int l  = threadIdx.x & 63;
    int br = tg / 304;
    int rem = tg % 304;
    int ks = rem / 16, ft = rem % 16;
    const float* src;
    switch (br) {
        case 0: src = w0; break;
        case 1: src = w1; break;
        case 2: src = w2; break;
        case 3: src = w3; break;
        default: src = w4; break;
    }
    int f = ft * 16 + (l & 15);
    int k0 = ks * 32 + (l >> 4) * 8;
    bf16x8 v;
#pragma unroll
    for (int e = 0; e < 8; e++) {
        int k = k0 + e;
        v[e] = (k < 600) ? (bf16_t)src[(size_t)f * 600 + k] : (bf16_t)0.f;
    }
    *(bf16x8*)(wp + (size_t)br * FNUM * KPAD + ((size_t)(ks * 16 + ft) * 512 + (size_t)l * 8)) = v;
}

// ---------------- K-loop over one 32-t chunk; optional async stage of next chunk at ks==3 ----------------
// 8 waves; wave w owns f [32w, 32w+32) (W tiles 2w, 2w+1). X is f32 in LDS, converted to
// bf16 at fragment-read time. Staging uses global_load_lds: zero VGPR cost.
__device__ __forceinline__ void kloop_f32(const bf16_t* __restrict__ wa,
        const float* __restrict__ bufR, f32x4 (&acc)[2][2], const int nf,
        const int l15, const int g,
        const bool doStage, const float* __restrict__ srcN, const int bytesN,
        float* __restrict__ dstN, const int tid) {
    const int bo = l15 * 300 + g * 8;
#pragma unroll
    for (int ks = 0; ks < NKS; ++ks) {
        if (doStage && ks == 3) {
#pragma unroll
            for (int q = 0; q < 5; ++q) {
                const int off = (tid + q * 512) * 16;
                if (off < bytesN) {
                    __builtin_amdgcn_global_load_lds(
                        (const __attribute__((address_space(1))) void*)((const char*)srcN + off),
                        (__attribute__((address_space(3))) void*)((char*)dstN + off),
                        16, 0, 0);
                }
            }
        }
        const bf16_t* wk = wa + (size_t)ks * (16 * 512);
        bf16x8 a0 = *(const bf16x8*)(wk);
        bf16x8 a1 = *(const bf16x8*)(wk + 512);
#pragma unroll
        for (int j = 0; j < 2; ++j) {
            if (j < nf) {
                const float* p = bufR + bo + j * (16 * 300) + ks * 32;
                float4 lo = *(const float4*)(p);
                float4 hi = *(const float4*)(p + 4);
                bf16x8 bb = { (bf16_t)lo.x, (bf16_t)lo.y, (bf16_t)lo.z, (bf16_t)lo.w,
                              (bf16_t)hi.x, (bf16_t)hi.y, (bf16_t)hi.z, (bf16_t)hi.w };
                acc[0][j] = __builtin_amdgcn_mfma_f32_16x16x32_bf16(a0, bb, acc[0][j], 0, 0, 0);
                acc[1][j] = __builtin_amdgcn_mfma_f32_16x16x32_bf16(a1, bb, acc[1][j], 0, 0, 0);
            }
        }
    }
}

__device__ __forceinline__ void stage_async(const float* __restrict__ src, const int bytes,
                                            float* __restrict__ dst, const int tid) {
#pragma unroll
    for (int q = 0; q < 5; ++q) {
        const int off = (tid + q * 512) * 16;
        if (off < bytes) {
            __builtin_amdgcn_global_load_lds(
                (const __attribute__((address_space(1))) void*)((const char*)src + off),
                (__attribute__((address_space(3))) void*)((char*)dst + off),
                16, 0, 0);
        }
    }
}

// ---------------- body conv: grid 1031; bid<1024 = batch (7 chunks of 32t, dbuf, pipelined);
// bid>=1024 = doc chunk (bid-1024) -> partial sums to mdp ----------------
__global__ __launch_bounds__(512, 4)
void conv_body(const float* __restrict__ X, const bf16_t* __restrict__ Wsw,
               const float* __restrict__ bias, float* __restrict__ nebT,
               const float* __restrict__ Xdoc, const bf16_t* __restrict__ Wdoc,
               const float* __restrict__ bdoc, float* __restrict__ mdp) {
    __shared__ alignas(16) float Xl[2][BUFF];
    __shared__ float feat[256];
    __shared__ float red[8];
    const int tid = threadIdx.x, l = tid & 63, w = tid >> 6, g = l >> 4, l15 = l & 15;
    const bool rider = ((int)blockIdx.x >= 1024);

    const float*  Xb = rider ? Xdoc : X + (size_t)blockIdx.x * 60000;
    const bf16_t* Wb = rider ? Wdoc : Wsw;
    const float*  bp = rider ? bdoc : bias;
    const bf16_t* wa = Wb + (size_t)(2 * w) * 512 + (size_t)l * 8;

    // zero the 8-f32 guards of both buffers (k=600..607 overrun, multiplied by W=0)
    if (tid < 16) Xl[tid >> 3][33 * 300 + (tid & 7)] = 0.f;

    const int cFirst = rider ? ((int)blockIdx.x - 1024) : 0;
    const int cCount = rider ? 1 : 7;

    // prologue: zero tail (rider short chunks), then async-stage chunk cFirst into buf0
    {
        const int rem = 200 - 32 * cFirst;
        const int rows0 = (rem < 33) ? rem : 33;
        for (int v = rows0 * 300 + tid; v < 33 * 300; v += 512) Xl[0][v] = 0.f;
        stage_async(Xb + (size_t)(32 * cFirst) * 300, rows0 * 1200, &Xl[0][0], tid);
    }
    __syncthreads();

    float run[2][4] = {{0.f,0.f,0.f,0.f},{0.f,0.f,0.f,0.f}};
    int pp = 0;
    for (int cc = 0; cc < cCount; ++cc) {
        const int c  = cFirst + cc;
        const int nf = (c < 6) ? 2 : 1;

        const bool doStage = (cc + 1 < cCount);
        const float* srcN = nullptr;
        int bytesN = 0;
        if (doStage) {
            const int c1 = c + 1;
            const int rem1 = 200 - 32 * c1;
            const int rows1 = (rem1 < 33) ? rem1 : 33;
            srcN = Xb + (size_t)(32 * c1) * 300;
            bytesN = rows1 * 1200;
        }

        f32x4 acc[2][2];
#pragma unroll
        for (int i = 0; i < 2; i++)
#pragma unroll
            for (int j = 0; j < 2; j++) acc[i][j] = (f32x4){0.f, 0.f, 0.f, 0.f};

        kloop_f32(wa, &Xl[pp][0], acc, nf, l15, g, doStage, srcN, bytesN, &Xl[pp ^ 1][0], tid);

        // epilogue: relu(acc+bias), t-mask, accumulate
#pragma unroll
        for (int i = 0; i < 2; i++)
#pragma unroll
            for (int r = 0; r < 4; r++) {
                const float bi = bp[32 * w + i * 16 + g * 4 + r];
                float s = run[i][r];
#pragma unroll
                for (int j = 0; j < 2; j++) {
                    if (j < nf) {
                        int t = 32 * c + j * 16 + l15;
                        float v = acc[i][j][r] + bi;
                        v = fmaxf(v, 0.f);
                        s += (t < 199) ? v : 0.f;
                    }
                }
                run[i][r] = s;
            }
        __syncthreads();   // drains staged loads; protects buffer swap
        pp ^= 1;
    }

    // cross-lane t-reduce -> feat
#pragma unroll
    for (int i = 0; i < 2; i++)
#pragma unroll
        for (int r = 0; r < 4; r++) {
            float s = run[i][r];
            s += __shfl_xor(s, 1);
            s += __shfl_xor(s, 2);
            s += __shfl_xor(s, 4);
            s += __shfl_xor(s, 8);
            if (l15 == 0) feat[32 * w + i * 16 + g * 4 + r] = s;
        }
    __syncthreads();

    if (rider) {
        if (tid < 256) mdp[(size_t)(blockIdx.x - 1024) * 256 + tid] = feat[tid];
        return;
    }
    float v = 0.f, sq = 0.f;
    if (tid < 256) { v = feat[tid]; sq = v * v; }
    sq += __shfl_xor(sq, 1);
    sq += __shfl_xor(sq, 2);
    sq += __shfl_xor(sq, 4);
    sq += __shfl_xor(sq, 8);
    sq += __shfl_xor(sq, 16);
    sq += __shfl_xor(sq, 32);
    if (l == 0) red[w] = sq;
    __syncthreads();
    float tot = red[0] + red[1] + red[2] + red[3];
    if (tid < 256) nebT[(size_t)tid * 1024 + blockIdx.x] = v / sqrtf(tot);
}

// ---------------- small branches (title/context/mention), one kernel, grid 1536 ----------------
__global__ __launch_bounds__(512, 4)
void conv_small(const float* __restrict__ title, const bf16_t* __restrict__ Wet,
                const float* __restrict__ bet, float* __restrict__ netT,
                const float* __restrict__ ctx, const bf16_t* __restrict__ Wmc,
                const float* __restrict__ bmc, float* __restrict__ nmc,
                const float* __restrict__ men, const bf16_t* __restrict__ Wms,
                const float* __restrict__ bms, float* __restrict__ nms) {
    __shared__ alignas(16) float Xs[BUFF];
    __shared__ float feat[256];
    __shared__ float red[8];
    const int tid = threadIdx.x, l = tid & 63, w = tid >> 6, g = l >> 4, l15 = l & 15;
    const int bid = blockIdx.x;

    const float* Xb; const bf16_t* Wb; const float* bp;
    int L, T, nf, batch, mode;
    if (bid < 1024)      { mode = 0; batch = bid;        Xb = title + (size_t)batch * 6000; Wb = Wet; bp = bet; L = 20; T = 19; nf = 2; }
    else if (bid < 1280) { mode = 1; batch = bid - 1024; Xb = ctx   + (size_t)batch * 6000; Wb = Wmc; bp = bmc; L = 20; T = 19; nf = 2; }
    else                 { mode = 2; batch = bid - 1280; Xb = men   + (size_t)batch * 3000; Wb = Wms; bp = bms; L = 10; T = 9;  nf = 1; }

    const bf16_t* wa = Wb + (size_t)(2 * w) * 512 + (size_t)l * 8;

    // zero tail (rows L..32 + guard), then async-stage rows [0, L)
    for (int v = L * 300 + tid; v < BUFF; v += 512) Xs[v] = 0.f;
    stage_async(Xb, L * 1200, Xs, tid);
    __syncthreads();

    f32x4 acc[2][2];
#pragma unroll
    for (int i = 0; i < 2; i++)
#pragma unroll
        for (int j = 0; j < 2; j++) acc[i][j] = (f32x4){0.f, 0.f, 0.f, 0.f};

    kloop_f32(wa, Xs, acc, nf, l15, g, false, nullptr, 0, nullptr, tid);

#pragma unroll
    for (int i = 0; i < 2; i++)
#pragma unroll
        for (int r = 0; r < 4; r++) {
            const float bi = bp[32 * w + i * 16 + g * 4 + r];
            float s = 0.f;
#pragma unroll
            for (int j = 0; j < 2; j++) {
                if (j < nf) {
                    int t = j * 16 + l15;
                    float v = acc[i][j][r] + bi;
                    v = fmaxf(v, 0.f);
                    s += (t < T) ? v : 0.f;
                }
            }
            s += __shfl_xor(s, 1);
            s += __shfl_xor(s, 2);
            s += __shfl_xor(s, 4);
            s += __shfl_xor(s, 8);
            if (l15 == 0) feat[32 * w + i * 16 + g * 4 + r] = s;
        }
    __syncthreads();

    float v = 0.f, sq = 0.f;
    if (tid < 256) { v = feat[tid]; sq = v * v; }
    sq += __shfl_xor(sq, 1);
    sq += __shfl_xor(sq, 2);
    sq += __shfl_xor(sq, 4);
    sq += __shfl_xor(sq, 8);
    sq += __shfl_xor(sq, 16);
    sq += __shfl_xor(sq, 32);
    if (l == 0) red[w] = sq;
    __syncthreads();
    float tot = red[0] + red[1] + red[2] + red[3];
    if (tid < 256) {
        float o = v / sqrtf(tot);
        if (mode == 0)      netT[(size_t)tid * 1024 + batch] = o;
        else if (mode == 1) nmc[(size_t)batch * 256 + tid] = o;
        else                nms[(size_t)batch * 256 + tid] = o;
    }
}

// ---------------- dt/db: combine 7 doc partials, normalize, dot with netT/nebT columns ----------------
__global__ __launch_bounds__(256)
void dt_db_kernel(const float* __restrict__ mdp, const float* __restrict__ netT,
                  const float* __restrict__ nebT, float* __restrict__ dt,
                  float* __restrict__ db) {
    __shared__ float md[256];
    __shared__ float red[4];
    int tid = threadIdx.x;
    float m = 0.f;
#pragma unroll
    for (int c = 0; c < 7; ++c) m += mdp[c * 256 + tid];
    float sq = m * m;
    sq += __shfl_xor(sq, 1);
    sq += __shfl_xor(sq, 2);
    sq += __shfl_xor(sq, 4);
    sq += __shfl_xor(sq, 8);
    sq += __shfl_xor(sq, 16);
    sq += __shfl_xor(sq, 32);
    if ((tid & 63) == 0) red[tid >> 6] = sq;
    __syncthreads();
    float rn = 1.f / sqrtf(red[0] + red[1] + red[2] + red[3]);
    md[tid] = m * rn;
    __syncthreads();
    int n = blockIdx.x * 256 + tid;
    float dT = 0.f, dB = 0.f;
    for (int k = 0; k < 256; ++k) {
        float mk = md[k];
        dT += mk * netT[(size_t)k * 1024 + n];
        dB += mk * nebT[(size_t)k * 1024 + n];
    }
    dt[n] = dT;
    db[n] = dB;
}

// ---------------- pair pass 1: tile 4m x 256n per block (grid 256) ----------------
__global__ __launch_bounds__(256)
void pair1(const float* __restrict__ nms, const float* __restrict__ nmc,
           const float* __restrict__ netT, const float* __restrict__ nebT,
           const float* __restrict__ dt, const float* __restrict__ db,
           const float* __restrict__ wl, const float* __restrict__ bl,
           const int* __restrict__ me, float* __restrict__ out,
           float* __restrict__ epart) {
    __shared__ float sA[4 * 256], sB[4 * 256];
    const int tid = threadIdx.x;
    const int mt = blockIdx.x >> 2;
    const int nt = blockIdx.x & 3;
    const int m0 = mt * 4, n0 = nt * 256;
    for (int v = tid; v < 1024; v += 256) {
        sA[v] = nms[(size_t)m0 * 256 + v];
        sB[v] = nmc[(size_t)m0 * 256 + v];
    }
    __syncthreads();
    const int ws = tid >> 6;
    const int nl = tid & 63;
    const int n  = n0 + nl * 4;
    const int m  = m0 + ws;

    float dst[4] = {0,0,0,0}, dct[4] = {0,0,0,0}, dsb[4] = {0,0,0,0}, dcb[4] = {0,0,0,0};
    for (int k = 0; k < 256; ++k) {
        float4 tv = *(const float4*)(netT + (size_t)k * 1024 + n);
        float4 bv = *(const float4*)(nebT + (size_t)k * 1024 + n);
        float a = sA[ws * 256 + k];
        float c = sB[ws * 256 + k];
        dst[0] += a * tv.x; dst[1] += a * tv.y; dst[2] += a * tv.z; dst[3] += a * tv.w;
        dct[0] += c * tv.x; dct[1] += c * tv.y; dct[2] += c * tv.z; dct[3] += c * tv.w;
        dsb[0] += a * bv.x; dsb[1] += a * bv.y; dsb[2] += a * bv.z; dsb[3] += a * bv.w;
        dcb[0] += c * bv.x; dcb[1] += c * bv.y; dcb[2] += c * bv.z; dcb[3] += c * bv.w;
    }

    float w0 = wl[0], w1 = wl[1], w2 = wl[2], w3 = wl[3], w4 = wl[4], w5 = wl[5], b = bl[0];
    float dtq[4], dbq[4];
    *(float4*)dtq = *(const float4*)(dt + n);
    *(float4*)dbq = *(const float4*)(db + n);
    const int* mp = me + (size_t)m * 1024 + n;
    float scv[4], evv[4];
    float esum = 0.f;
#pragma unroll
    for (int q = 0; q < 4; q++) {
        float msk = (float)mp[q];
        float f_st = dst[q] * 0.5f + 0.5f;
        float f_dt = dtq[q] * 0.5f + 0.5f;
        float f_ct = dct[q] * 0.5f + 0.5f;
        float f_sb = dsb[q] * 0.5f + 0.5f;
        float f_db = dbq[q] * 0.5f + 0.5f;
        float f_cb = dcb[q] * 0.5f + 0.5f;
        float s = f_st * w0 + f_dt * w1 + f_ct * w2 + f_sb * w3 + f_db * w4 + f_cb * w5 + b;
        s = (msk != 0.f) ? s : 0.f;
        scv[q] = s;
        evv[q] = (msk != 0.f) ? expf(s / 0.1f) : 0.f;
        esum += evv[q];
    }
    esum += __shfl_xor(esum, 1);
    esum += __shfl_xor(esum, 2);
    esum += __shfl_xor(esum, 4);
    esum += __shfl_xor(esum, 8);
    esum += __shfl_xor(esum, 16);
    esum += __shfl_xor(esum, 32);
    if (nl == 0) epart[(size_t)m * 4 + nt] = esum;

    *(float4*)(out + (size_t)m * 1024 + n) = *(float4*)scv;
    *(float4*)(out + 262144 + (size_t)m * 1024 + n) = *(float4*)evv;
}

// ---------------- pair pass 2: row-normalize e in place ----------------
__global__ __launch_bounds__(256)
void pair2(const float* __restrict__ epart, float* __restrict__ out2) {
    int m = blockIdx.x, tid = threadIdx.x;
    float tot = epart[(size_t)m * 4 + 0] + epart[(size_t)m * 4 + 1]
              + epart[(size_t)m * 4 + 2] + epart[(size_t)m * 4 + 3];
    float inv = 1.f / tot;
#pragma unroll
    for (int q = 0; q < 4; q++)
        out2[(size_t)m * 1024 + q * 256 + tid] *= inv;
}

extern "C" void kernel_launch(void* const* d_in, const int* in_sizes, int n_in,
                              void* d_out, int out_size, void* d_ws, size_t ws_size,
                              hipStream_t stream) {
    const float* mention = (const float*)d_in[0];
    const float* context = (const float*)d_in[1];
    const float* doc     = (const float*)d_in[2];
    const float* title   = (const float*)d_in[3];
    const float* body    = (const float*)d_in[4];
    const float* W_ms = (const float*)d_in[5];  const float* b_ms = (const float*)d_in[6];
    const float* W_mc = (const float*)d_in[7];  const float* b_mc = (const float*)d_in[8];
    const float* W_md = (const float*)d_in[9];  const float* b_md = (const float*)d_in[10];
    const float* W_et = (const float*)d_in[11]; const float* b_et = (const float*)d_in[12];
    const float* W_eb = (const float*)d_in[13]; const float* b_eb = (const float*)d_in[14];
    const float* w_local = (const float*)d_in[15];
    const float* b_local = (const float*)d_in[16];
    const int*   me      = (const int*)d_in[17];
    float* out = (float*)d_out;

    char* ws = (char*)d_ws;
    bf16_t* Wp = (bf16_t*)ws;
    size_t off = (size_t)5 * FNUM * KPAD * 2;             // swizzled W: 1,556,480 B
    float* nms  = (float*)(ws + off); off += 256 * 256 * 4;
    float* nmc  = (float*)(ws + off); off += 256 * 256 * 4;
    float* netT = (float*)(ws + off); off += 256 * 1024 * 4;
    float* nebT = (float*)(ws + off); off += 256 * 1024 * 4;
    float* mdp  = (float*)(ws + off); off += 7 * 256 * 4;
    float* dt   = (float*)(ws + off); off += 1024 * 4;
    float* db   = (float*)(ws + off); off += 1024 * 4;
    float* epart= (float*)(ws + off); off += 256 * 4 * 4;

    const bf16_t* Wms = Wp + (size_t)0 * FNUM * KPAD;
    const bf16_t* Wmc = Wp + (size_t)1 * FNUM * KPAD;
    const bf16_t* Wmd = Wp + (size_t)2 * FNUM * KPAD;
    const bf16_t* Wet = Wp + (size_t)3 * FNUM * KPAD;
    const bf16_t* Web = Wp + (size_t)4 * FNUM * KPAD;

    prep_w_swz<<<380, 256, 0, stream>>>(W_ms, W_mc, W_md, W_et, W_eb, Wp);

    conv_body<<<1031, 512, 0, stream>>>(body, Web, b_eb, nebT, doc, Wmd, b_md, mdp);
    conv_small<<<1536, 512, 0, stream>>>(title, Wet, b_et, netT,
                                         context, Wmc, b_mc, nmc,
                                         mention, Wms, b_ms, nms);

    dt_db_kernel<<<4, 256, 0, stream>>>(mdp, netT, nebT, dt, db);
    pair1<<<256, 256, 0, stream>>>(nms, nmc, netT, nebT, dt, db, w_local, b_local, me, out, epart);
    pair2<<<256, 256, 0, stream>>>(epart, out + 262144);
}

// Round 9
// 244.093 us; speedup vs baseline: 2.0232x; 1.8194x over previous
//
#include <hip/hip_runtime.h>
#include <math.h>

typedef __bf16 bf16_t;
typedef __bf16 bf16x4 __attribute__((ext_vector_type(4)));
typedef __bf16 bf16x8 __attribute__((ext_vector_type(8)));
typedef float  f32x4  __attribute__((ext_vector_type(4)));

#define FNUM 256
#define KPAD 608            // 600 padded to 608 (19 K-steps of 32)
#define NKS  19

// body chunk geometry: c0 = t 0..111 (nf=7, rows 0..113), c1 = t 112..207 (nf=6, rows 112..199)
#define BUFA_E 34200        // 114 rows * 300 bf16 (covers max read 33907)
#define BUFB_E 29120        // staged 88 rows (26400) + guard + garbage-read slack (max read 29107)
#define GUARD_OFF 26400     // 88*300: zero 16 bf16 here for t=198 k-overrun

// ---------------- W prep: f32 [256][600] -> swizzled bf16 MFMA-fragment tiles ----------------
// Tile (ks, ft): 64 lanes x 8 bf16 contiguous. lane l -> f = ft*16+(l&15), k = ks*32+(l>>4)*8+e.
__global__ __launch_bounds__(256)
void prep_w_swz(const float* __restrict__ w0, const float* __restrict__ w1,
                const float* __restrict__ w2, const float* __restrict__ w3,
                const float* __restrict__ w4, bf16_t* __restrict__ wp) {
    int tg = blockIdx.x * 4 + (threadIdx.x >> 6);    // 5*19*16 = 1520 tiles
    if (tg >= 1520) return;
    int l  = threadIdx.x & 63;
    int br = tg / 304;
    int rem = tg % 304;
    int ks = rem / 16, ft = rem % 16;
    const float* src;
    switch (br) {
        case 0: src = w0; break;
        case 1: src = w1; break;
        case 2: src = w2; break;
        case 3: src = w3; break;
        default: src = w4; break;
    }
    int f = ft * 16 + (l & 15);
    int k0 = ks * 32 + (l >> 4) * 8;
    bf16x8 v;
#pragma unroll
    for (int e = 0; e < 8; e++) {
        int k = k0 + e;
        v[e] = (k < 600) ? (bf16_t)src[(size_t)f * 600 + k] : (bf16_t)0.f;
    }
    *(bf16x8*)(wp + (size_t)br * FNUM * KPAD + ((size_t)(ks * 16 + ft) * 512 + (size_t)l * 8)) = v;
}

// ---------------- consumer K-loop: R4-proven pattern (bf16 LDS, depth-1 W prefetch) ----------------
template<int NFMAX>
__device__ __forceinline__ void kloop(const bf16_t* __restrict__ wa,
        const bf16_t* __restrict__ buf, f32x4 (&acc)[2][NFMAX],
        const int nf, const int (&boff)[NFMAX]) {
    bf16x8 aCur[2], aNxt[2];
    aCur[0] = *(const bf16x8*)(wa);
    aCur[1] = *(const bf16x8*)(wa + 512);
#pragma unroll
    for (int ks = 0; ks < NKS; ++ks) {
        if (ks + 1 < NKS) {
            const bf16_t* wn = wa + (size_t)(ks + 1) * (16 * 512);
            aNxt[0] = *(const bf16x8*)(wn);
            aNxt[1] = *(const bf16x8*)(wn + 512);
        }
        const int k0 = ks * 32;
#pragma unroll
        for (int j = 0; j < NFMAX; ++j) {
            if (j < nf) {
                const bf16_t* p = buf + boff[j] + k0;
                bf16x4 lo = *(const bf16x4*)(p);
                bf16x4 hi = *(const bf16x4*)(p + 4);
                bf16x8 bb = __builtin_shufflevector(lo, hi, 0, 1, 2, 3, 4, 5, 6, 7);
                acc[0][j] = __builtin_amdgcn_mfma_f32_16x16x32_bf16(aCur[0], bb, acc[0][j], 0, 0, 0);
                acc[1][j] = __builtin_amdgcn_mfma_f32_16x16x32_bf16(aCur[1], bb, acc[1][j], 0, 0, 0);
            }
        }
        aCur[0] = aNxt[0]; aCur[1] = aNxt[1];
    }
}

// ---------------- producer stage: flat f32->bf16 copy, 8 loads in flight, 256 producer lanes ----------------
__device__ __forceinline__ void stage8(bf16_t* __restrict__ dst, const float* __restrict__ src,
                                       const int rows, const int lane256) {
    const float4* s4 = (const float4*)src;
    const int nv = rows * 75;
    for (int v0 = lane256; v0 < nv; v0 += 2048) {
        float4 t[8];
#pragma unroll
        for (int k = 0; k < 8; ++k) {
            int v = v0 + k * 256;
            if (v < nv) t[k] = s4[v];
        }
#pragma unroll
        for (int k = 0; k < 8; ++k) {
            int v = v0 + k * 256;
            if (v < nv) {
                bf16x4 h = { (bf16_t)t[k].x, (bf16_t)t[k].y, (bf16_t)t[k].z, (bf16_t)t[k].w };
                *(bf16x4*)(dst + (size_t)v * 4) = h;
            }
        }
    }
}

// ---------------- body conv: persistent grid 256 x 768 (8 consumer + 4 producer waves) ----------------
__global__ __launch_bounds__(768, 3)
void conv_body(const float* __restrict__ X, const bf16_t* __restrict__ Web,
               const float* __restrict__ beb, float* __restrict__ nebT,
               const float* __restrict__ Xdoc, const bf16_t* __restrict__ Wmd,
               const float* __restrict__ bmd, float* __restrict__ mdp) {
    __shared__ bf16_t bufA[BUFA_E];
    __shared__ bf16_t bufB[BUFB_E];
    __shared__ float feat[256];
    __shared__ float red[4];

    const int tid = threadIdx.x, l = tid & 63, w = tid >> 6, g = l >> 4, l15 = l & 15;
    const bool cons = (w < 8);
    const int bid = (int)blockIdx.x;
    const int nChunk = (bid >= 254) ? 9 : 8;

    auto chunkSrc = [&](int i, int& rows, int& nf, int& t0, bool& guard, bool& isDoc) -> const float* {
        int half;
        const float* base;
        if (i < 8) { int batch = bid * 4 + (i >> 1); half = i & 1; base = X + (size_t)batch * 60000; isDoc = false; }
        else       { half = bid - 254; base = Xdoc; isDoc = true; }
        rows = half ? 88 : 114; nf = half ? 6 : 7; t0 = half * 112; guard = (half != 0);
        return base + half * 33600;
    };

    if (!cons) {
        int rows, nf, t0; bool guard, isDoc;
        const float* s = chunkSrc(0, rows, nf, t0, guard, isDoc);
        stage8(bufA, s, rows, (w - 8) * 64 + l);
    }
    __syncthreads();

    float run[2][4];
    for (int i = 0; i < nChunk; ++i) {
        int rows, nf, t0; bool guard, isDoc;
        const float* src = chunkSrc(i, rows, nf, t0, guard, isDoc);
        (void)src; (void)rows; (void)guard;
        const bf16_t* buf = (i & 1) ? bufB : bufA;
        const bf16_t* Wb = isDoc ? Wmd : Web;
        const float* bp = isDoc ? bmd : beb;

        if (cons) {
            if ((i & 1) == 0) {
#pragma unroll
                for (int a = 0; a < 2; a++)
#pragma unroll
                    for (int r = 0; r < 4; r++) run[a][r] = 0.f;
            }
            int boff[7];
#pragma unroll
            for (int j = 0; j < 7; ++j) boff[j] = (j * 16 + l15) * 300 + g * 8;

            f32x4 acc[2][7];
#pragma unroll
            for (int a = 0; a < 2; a++)
#pragma unroll
                for (int j = 0; j < 7; j++) acc[a][j] = (f32x4){0.f, 0.f, 0.f, 0.f};

            const bf16_t* wa = Wb + (size_t)(2 * w) * 512 + (size_t)l * 8;
            kloop<7>(wa, buf, acc, nf, boff);

#pragma unroll
            for (int a = 0; a < 2; a++)
#pragma unroll
                for (int r = 0; r < 4; r++) {
                    const float bi = bp[32 * w + a * 16 + g * 4 + r];
                    float s = run[a][r];
#pragma unroll
                    for (int j = 0; j < 7; j++) {
                        if (j < nf) {
                            int t = t0 + j * 16 + l15;
                            float v = acc[a][j][r] + bi;
                            v = fmaxf(v, 0.f);
                            s += (t < 199) ? v : 0.f;
                        }
                    }
                    run[a][r] = s;
                }
        } else {
            if (i + 1 < nChunk) {
                int rows1, nf1, t01; bool guard1, isDoc1;
                const float* s1 = chunkSrc(i + 1, rows1, nf1, t01, guard1, isDoc1);
                bf16_t* nb = ((i + 1) & 1) ? bufB : bufA;
                const int lane256 = (w - 8) * 64 + l;
                stage8(nb, s1, rows1, lane256);
                if (guard1 && lane256 < 4) {
                    bf16x4 z = { (bf16_t)0.f, (bf16_t)0.f, (bf16_t)0.f, (bf16_t)0.f };
                    *(bf16x4*)(nb + GUARD_OFF + lane256 * 4) = z;
                }
            }
        }
        __syncthreads();

        const bool bEnd = (i == 8) || ((i & 1) == 1);
        if (bEnd) {
            if (cons) {
#pragma unroll
                for (int a = 0; a < 2; a++)
#pragma unroll
                    for (int r = 0; r < 4; r++) {
                        float s = run[a][r];
                        s += __shfl_xor(s, 1);
                        s += __shfl_xor(s, 2);
                        s += __shfl_xor(s, 4);
                        s += __shfl_xor(s, 8);
                        if (l15 == 0) feat[32 * w + a * 16 + g * 4 + r] = s;
                    }
            }
            __syncthreads();
            if (isDoc) {
                if (tid < 256) mdp[(size_t)(bid - 254) * 256 + tid] = feat[tid];
            } else {
                float v = 0.f, sq = 0.f;
                if (tid < 256) { v = feat[tid]; sq = v * v; }
                sq += __shfl_xor(sq, 1);
                sq += __shfl_xor(sq, 2);
                sq += __shfl_xor(sq, 4);
                sq += __shfl_xor(sq, 8);
                sq += __shfl_xor(sq, 16);
                sq += __shfl_xor(sq, 32);
                if (tid < 256 && l == 0) red[w] = sq;
                __syncthreads();
                if (tid < 256) {
                    float tot = red[0] + red[1] + red[2] + red[3];
                    int batch = bid * 4 + (i >> 1);
                    nebT[(size_t)tid * 1024 + batch] = v / sqrtf(tot);
                }
            }
        }
    }
}

// ---------------- small branches: 4 batches per block, all indices compile-time ----------------
template<int NFB, int L, int T, int BSTR, int ARRE>
__global__ __launch_bounds__(512, 4)
void conv_small(const float* __restrict__ XA, const bf16_t* __restrict__ WA,
                const float* __restrict__ bA, float* __restrict__ outA,
                const float* __restrict__ XB, const bf16_t* __restrict__ WB,
                const float* __restrict__ bB, float* __restrict__ outB,
                int nABlocks) {
    constexpr int NTOT = 4 * NFB;
    __shared__ bf16_t Xs[ARRE];
    __shared__ float feat4[4][256];

    const int tid = threadIdx.x, l = tid & 63, w = tid >> 6, g = l >> 4, l15 = l & 15;
    const bool modeA = ((int)blockIdx.x < nABlocks);
    const int grp = modeA ? (int)blockIdx.x : ((int)blockIdx.x - nABlocks);
    const int batch0 = grp * 4;
    const float* Xsrc = modeA ? XA : XB;
    const bf16_t* Wb = modeA ? WA : WB;
    const float* bp = modeA ? bA : bB;

#pragma unroll
    for (int b = 0; b < 4; ++b) {
        const float4* s4 = (const float4*)(Xsrc + (size_t)(batch0 + b) * (L * 300));
        for (int v = tid; v < L * 75; v += 512) {
            float4 f = s4[v];
            bf16x4 h = { (bf16_t)f.x, (bf16_t)f.y, (bf16_t)f.z, (bf16_t)f.w };
            *(bf16x4*)(Xs + b * BSTR + v * 4) = h;
        }
        if (tid < 2) {
            bf16x4 z = { (bf16_t)0.f, (bf16_t)0.f, (bf16_t)0.f, (bf16_t)0.f };
            *(bf16x4*)(Xs + b * BSTR + L * 300 + tid * 4) = z;
        }
    }
    __syncthreads();

    int boff[NTOT];
#pragma unroll
    for (int j = 0; j < NTOT; ++j)
        boff[j] = (j / NFB) * BSTR + ((j % NFB) * 16 + l15) * 300 + g * 8;

    f32x4 acc[2][NTOT];
#pragma unroll
    for (int a = 0; a < 2; a++)
#pragma unroll
        for (int j = 0; j < NTOT; j++) acc[a][j] = (f32x4){0.f, 0.f, 0.f, 0.f};

    const bf16_t* wa = Wb + (size_t)(2 * w) * 512 + (size_t)l * 8;
    kloop<NTOT>(wa, Xs, acc, NTOT, boff);

#pragma unroll
    for (int jb = 0; jb < 4; ++jb) {
#pragma unroll
        for (int a = 0; a < 2; a++)
#pragma unroll
            for (int r = 0; r < 4; r++) {
                const float bi = bp[32 * w + a * 16 + g * 4 + r];
                float s = 0.f;
#pragma unroll
                for (int jf = 0; jf < NFB; ++jf) {
                    int t = jf * 16 + l15;
                    float v = acc[a][jb * NFB + jf][r] + bi;
                    v = fmaxf(v, 0.f);
                    s += (t < T) ? v : 0.f;
                }
                s += __shfl_xor(s, 1);
                s += __shfl_xor(s, 2);
                s += __shfl_xor(s, 4);
                s += __shfl_xor(s, 8);
                if (l15 == 0) feat4[jb][32 * w + a * 16 + g * 4 + r] = s;
            }
    }
    __syncthreads();

    if (w < 4) {
        float vv[4];
        float sq = 0.f;
#pragma unroll
        for (int q = 0; q < 4; q++) { vv[q] = feat4[w][l * 4 + q]; sq += vv[q] * vv[q]; }
        sq += __shfl_xor(sq, 1);
        sq += __shfl_xor(sq, 2);
        sq += __shfl_xor(sq, 4);
        sq += __shfl_xor(sq, 8);
        sq += __shfl_xor(sq, 16);
        sq += __shfl_xor(sq, 32);
        float rsq = 1.f / sqrtf(sq);
        int batch = batch0 + w;
        if (modeA) {
#pragma unroll
            for (int q = 0; q < 4; q++)
                outA[(size_t)(l * 4 + q) * 1024 + batch] = vv[q] * rsq;
        } else {
            float4 o = { vv[0] * rsq, vv[1] * rsq, vv[2] * rsq, vv[3] * rsq };
            *(float4*)(outB + (size_t)batch * 256 + l * 4) = o;
        }
    }
}

// ---------------- dt/db ----------------
__global__ __launch_bounds__(256)
void dt_db_kernel(const float* __restrict__ mdp, const float* __restrict__ netT,
                  const float* __restrict__ nebT, float* __restrict__ dt,
                  float* __restrict__ db) {
    __shared__ float md[256];
    __shared__ float red[4];
    int tid = threadIdx.x;
    float m = mdp[tid] + mdp[256 + tid];
    float sq = m * m;
    sq += __shfl_xor(sq, 1);
    sq += __shfl_xor(sq, 2);
    sq += __shfl_xor(sq, 4);
    sq += __shfl_xor(sq, 8);
    sq += __shfl_xor(sq, 16);
    sq += __shfl_xor(sq, 32);
    if ((tid & 63) == 0) red[tid >> 6] = sq;
    __syncthreads();
    float rn = 1.f / sqrtf(red[0] + red[1] + red[2] + red[3]);
    md[tid] = m * rn;
    __syncthreads();
    int n = blockIdx.x * 256 + tid;
    float dT = 0.f, dB = 0.f;
    for (int k = 0; k < 256; ++k) {
        float mk = md[k];
        dT += mk * netT[(size_t)k * 1024 + n];
        dB += mk * nebT[(size_t)k * 1024 + n];
    }
    dt[n] = dT;
    db[n] = dB;
}

// ---------------- pair pass 1 ----------------
__global__ __launch_bounds__(256)
void pair1(const float* __restrict__ nms, const float* __restrict__ nmc,
           const float* __restrict__ netT, const float* __restrict__ nebT,
           const float* __restrict__ dt, const float* __restrict__ db,
           const float* __restrict__ wl, const float* __restrict__ bl,
           const int* __restrict__ me, float* __restrict__ out,
           float* __restrict__ epart) {
    __shared__ float sA[4 * 256], sB[4 * 256];
    const int tid = threadIdx.x;
    const int mt = blockIdx.x >> 2;
    const int nt = blockIdx.x & 3;
    const int m0 = mt * 4, n0 = nt * 256;
    for (int v = tid; v < 1024; v += 256) {
        sA[v] = nms[(size_t)m0 * 256 + v];
        sB[v] = nmc[(size_t)m0 * 256 + v];
    }
    __syncthreads();
    const int ws = tid >> 6;
    const int nl = tid & 63;
    const int n  = n0 + nl * 4;
    const int m  = m0 + ws;

    float dst[4] = {0,0,0,0}, dct[4] = {0,0,0,0}, dsb[4] = {0,0,0,0}, dcb[4] = {0,0,0,0};
    for (int k = 0; k < 256; ++k) {
        float4 tv = *(const float4*)(netT + (size_t)k * 1024 + n);
        float4 bv = *(const float4*)(nebT + (size_t)k * 1024 + n);
        float a = sA[ws * 256 + k];
        float c = sB[ws * 256 + k];
        dst[0] += a * tv.x; dst[1] += a * tv.y; dst[2] += a * tv.z; dst[3] += a * tv.w;
        dct[0] += c * tv.x; dct[1] += c * tv.y; dct[2] += c * tv.z; dct[3] += c * tv.w;
        dsb[0] += a * bv.x; dsb[1] += a * bv.y; dsb[2] += a * bv.z; dsb[3] += a * bv.w;
        dcb[0] += c * bv.x; dcb[1] += c * bv.y; dcb[2] += c * bv.z; dcb[3] += c * bv.w;
    }

    float w0 = wl[0], w1 = wl[1], w2 = wl[2], w3 = wl[3], w4 = wl[4], w5 = wl[5], b = bl[0];
    float dtq[4], dbq[4];
    *(float4*)dtq = *(const float4*)(dt + n);
    *(float4*)dbq = *(const float4*)(db + n);
    const int* mp = me + (size_t)m * 1024 + n;
    float scv[4], evv[4];
    float esum = 0.f;
#pragma unroll
    for (int q = 0; q < 4; q++) {
        float msk = (float)mp[q];
        float f_st = dst[q] * 0.5f + 0.5f;
        float f_dt = dtq[q] * 0.5f + 0.5f;
        float f_ct = dct[q] * 0.5f + 0.5f;
        float f_sb = dsb[q] * 0.5f + 0.5f;
        float f_db = dbq[q] * 0.5f + 0.5f;
        float f_cb = dcb[q] * 0.5f + 0.5f;
        float s = f_st * w0 + f_dt * w1 + f_ct * w2 + f_sb * w3 + f_db * w4 + f_cb * w5 + b;
        s = (msk != 0.f) ? s : 0.f;
        scv[q] = s;
        evv[q] = (msk != 0.f) ? expf(s / 0.1f) : 0.f;
        esum += evv[q];
    }
    esum += __shfl_xor(esum, 1);
    esum += __shfl_xor(esum, 2);
    esum += __shfl_xor(esum, 4);
    esum += __shfl_xor(esum, 8);
    esum += __shfl_xor(esum, 16);
    esum += __shfl_xor(esum, 32);
    if (nl == 0) epart[(size_t)m * 4 + nt] = esum;

    *(float4*)(out + (size_t)m * 1024 + n) = *(float4*)scv;
    *(float4*)(out + 262144 + (size_t)m * 1024 + n) = *(float4*)evv;
}

// ---------------- pair pass 2 ----------------
__global__ __launch_bounds__(256)
void pair2(const float* __restrict__ epart, float* __restrict__ out2) {
    int m = blockIdx.x, tid = threadIdx.x;
    float tot = epart[(size_t)m * 4 + 0] + epart[(size_t)m * 4 + 1]
              + epart[(size_t)m * 4 + 2] + epart[(size_t)m * 4 + 3];
    float inv = 1.f / tot;
#pragma unroll
    for (int q = 0; q < 4; q++)
        out2[(size_t)m * 1024 + q * 256 + tid] *= inv;
}

extern "C" void kernel_launch(void* const* d_in, const int* in_sizes, int n_in,
                              void* d_out, int out_size, void* d_ws, size_t ws_size,
                              hipStream_t stream) {
    const float* mention = (const float*)d_in[0];
    const float* context = (const float*)d_in[1];
    const float* doc     = (const float*)d_in[2];
    const float* title   = (const float*)d_in[3];
    const float* body    = (const float*)d_in[4];
    const float* W_ms = (const float*)d_in[5];  const float* b_ms = (const float*)d_in[6];
    const float* W_mc = (const float*)d_in[7];  const float* b_mc = (const float*)d_in[8];
    const float* W_md = (const float*)d_in[9];  const float* b_md = (const float*)d_in[10];
    const float* W_et = (const float*)d_in[11]; const float* b_et = (const float*)d_in[12];
    const float* W_eb = (const float*)d_in[13]; const float* b_eb = (const float*)d_in[14];
    const float* w_local = (const float*)d_in[15];
    const float* b_local = (const float*)d_in[16];
    const int*   me      = (const int*)d_in[17];
    float* out = (float*)d_out;

    char* ws = (char*)d_ws;
    bf16_t* Wp = (bf16_t*)ws;
    size_t off = (size_t)5 * FNUM * KPAD * 2;
    float* nms  = (float*)(ws + off); off += 256 * 256 * 4;
    float* nmc  = (float*)(ws + off); off += 256 * 256 * 4;
    float* netT = (float*)(ws + off); off += 1024 * 256 * 4;
    float* nebT = (float*)(ws + off); off += 1024 * 256 * 4;
    float* mdp  = (float*)(ws + off); off += 2 * 256 * 4;
    float* dt   = (float*)(ws + off); off += 1024 * 4;
    float* db   = (float*)(ws + off); off += 1024 * 4;
    float* epart= (float*)(ws + off); off += 256 * 4 * 4;

    const bf16_t* Wms = Wp + (size_t)0 * FNUM * KPAD;
    const bf16_t* Wmc = Wp + (size_t)1 * FNUM * KPAD;
    const bf16_t* Wmd = Wp + (size_t)2 * FNUM * KPAD;
    const bf16_t* Wet = Wp + (size_t)3 * FNUM * KPAD;
    const bf16_t* Web = Wp + (size_t)4 * FNUM * KPAD;

    prep_w_swz<<<380, 256, 0, stream>>>(W_ms, W_mc, W_md, W_et, W_eb, Wp);

    conv_body<<<256, 768, 0, stream>>>(body, Web, b_eb, nebT, doc, Wmd, b_md, mdp);

    conv_small<2, 20, 19, 6016, 27968><<<320, 512, 0, stream>>>(
        title, Wet, b_et, netT, context, Wmc, b_mc, nmc, 256);
    conv_small<1, 10, 9, 5120, 20480><<<64, 512, 0, stream>>>(
        mention, Wms, b_ms, netT, mention, Wms, b_ms, nms, 0);

    dt_db_kernel<<<4, 256, 0, stream>>>(mdp, netT, nebT, dt, db);
    pair1<<<256, 256, 0, stream>>>(nms, nmc, netT, nebT, dt, db, w_local, b_local, me, out, epart);
    pair2<<<256, 256, 0, stream>>>(epart, out + 262144);
}